// Round 12
// baseline (162.813 us; speedup 1.0000x reference)
//
#include <hip/hip_runtime.h>
#include <hip/hip_fp16.h>
#include <math.h>

constexpr int kNodes = 50000;
constexpr int kEdges = 600000;
constexpr int kF     = 128;
constexpr int kNPB   = 64;        // nodes per block in gemm phase
constexpr int kCap   = 48;        // fixed bucket capacity; P(deg>=48) ~ 3e-15/node
constexpr int kStr   = 136;       // LDS row stride in fp16 (272B: 16B-aligned, 2-way banks)
constexpr int kCPad  = 16;        // cursor pad: one counter per 64B line

constexpr int kGemmB = (kNodes + kNPB - 1) / kNPB;   // 782
constexpr int kFillB = (kEdges + 255) / 256;         // 2344

// workspace layout (bytes)
constexpr size_t kOffWt     = 0;                          //  64 KB (fallback path only)
constexpr size_t kOffCursor = 65536;                      // 3.2 MB padded cursors
constexpr size_t kOffBucket = 65536 + 3200000;            // 9.6 MB
constexpr size_t kOffGpk    = kOffBucket + (size_t)kNodes * kCap * 4;   // 12.8 MB, 16B-aligned
constexpr size_t kWsNeeded  = kOffGpk + (size_t)kNodes * kF * 2;        // ~25 MiB

typedef _Float16 v8h __attribute__((ext_vector_type(8)));
typedef float    v4f __attribute__((ext_vector_type(4)));

static __device__ __forceinline__ unsigned int packh2(float a, float b) {
    __half2 h = __floats2half2_rn(a, b);
    return *reinterpret_cast<unsigned int*>(&h);
}

// ---------------------------------------------------------------------------
// Kernel 0: zero padded bucket cursors (64B/node) + Wt transpose (fallback).
__global__ __launch_bounds__(256) void prep0(const float* __restrict__ W,
                                             float* __restrict__ Wt,
                                             int* __restrict__ cursor) {
    int gid = blockIdx.x * 256 + threadIdx.x;    // grid covers 50176
    if (gid < kF * kF) {
        int k = gid >> 7;
        int o = gid & (kF - 1);
        Wt[gid] = W[o * kF + k];
    }
    if (gid < kNodes) {
        uint4 z = {0, 0, 0, 0};
        uint4* c4 = reinterpret_cast<uint4*>(cursor) + gid * 4;   // 64B line
        c4[0] = z; c4[1] = z; c4[2] = z; c4[3] = z;
    }
}

// ---------------------------------------------------------------------------
// Kernel 1 (fused): blocks [0,kFillB) scatter src ids into dst buckets
// (FIRST, so their atomic latency chains start early and overlap the GEMM);
// blocks [kFillB,...) compute G = F @ W^T via MFMA fp16, packed row-major.
// Cursor padded to one counter per 64B line: same-line atomic serialization
// (R11's ~20us fill floor: 192 atomics/line x ~100ns) drops to deg<=~35/line.
__global__ __launch_bounds__(256, 3) void gemm_fill(const float* __restrict__ F,
                                                    const float* __restrict__ Wg,
                                                    const int* __restrict__ src,
                                                    const int* __restrict__ dst,
                                                    int* __restrict__ cursor,
                                                    int* __restrict__ bucket,
                                                    uint2* __restrict__ Gpk2) {
    __shared__ __align__(16) unsigned short sW[kF * kStr];     // 34.8 KB
    __shared__ __align__(16) unsigned short sF[kNPB * kStr];   // 17.4 KB

    const int t = threadIdx.x;

    if (blockIdx.x < kFillB) {
        // ---- bucket-fill phase ----
        int e = blockIdx.x * 256 + t;
        if (e < kEdges) {
            int d = dst[e];
            int p = atomicAdd(&cursor[d * kCPad], 1);
            if (p < kCap) bucket[d * kCap + p] = src[e];   // guard: never triggers
        }
        return;
    }

    // ---- GEMM phase ----
    const int n0 = (blockIdx.x - kFillB) * kNPB;
    const int rows = min(kNPB, kNodes - n0);

    // stage W (fp32 global, L2-hot) -> fp16 LDS row-major, stride kStr
    for (int idx = t; idx < kF * 16; idx += 256) {       // 8 iters
        int o = idx >> 4, c = idx & 15;
        const float4* wp = reinterpret_cast<const float4*>(Wg + o * kF + c * 8);
        float4 w0 = wp[0], w1 = wp[1];
        uint4 pk;
        pk.x = packh2(w0.x, w0.y);
        pk.y = packh2(w0.z, w0.w);
        pk.z = packh2(w1.x, w1.y);
        pk.w = packh2(w1.z, w1.w);
        *reinterpret_cast<uint4*>(&sW[o * kStr + c * 8]) = pk;
    }
    // stage this block's F rows -> fp16 LDS row-major, stride kStr
    for (int idx = t; idx < rows * 16; idx += 256) {     // 4 iters
        int n = idx >> 4, c = idx & 15;
        const float4* fp = reinterpret_cast<const float4*>(F + (size_t)(n0 + n) * kF + c * 8);
        float4 f0 = fp[0], f1 = fp[1];
        uint4 pk;
        pk.x = packh2(f0.x, f0.y);
        pk.y = packh2(f0.z, f0.w);
        pk.z = packh2(f1.x, f1.y);
        pk.w = packh2(f1.z, f1.w);
        *reinterpret_cast<uint4*>(&sF[n * kStr + c * 8]) = pk;
    }
    __syncthreads();

    const int wv   = t >> 6;       // wave id 0..3 -> node-tile
    const int lane = t & 63;
    const int m    = lane & 15;    // within-tile row/col index
    const int quad = lane >> 4;    // 0..3

    // B-frags: this wave's 16 F rows, all 4 K-chunks (reused across 8 out-tiles)
    v8h bfrag[4];
#pragma unroll
    for (int kc = 0; kc < 4; ++kc)
        bfrag[kc] = *reinterpret_cast<const v8h*>(&sF[(wv * 16 + m) * kStr + kc * 32 + quad * 8]);

    const int node = n0 + wv * 16 + m;   // this lane's output node (D col)
#pragma unroll
    for (int ot = 0; ot < 8; ++ot) {
        v4f acc = {0.0f, 0.0f, 0.0f, 0.0f};
#pragma unroll
        for (int kc = 0; kc < 4; ++kc) {
            v8h afrag = *reinterpret_cast<const v8h*>(&sW[(ot * 16 + m) * kStr + kc * 32 + quad * 8]);
            acc = __builtin_amdgcn_mfma_f32_16x16x32_f16(afrag, bfrag[kc], acc, 0, 0, 0);
        }
        if (node < kNodes) {
            uint2 p;   // outs ot*16 + quad*4 + {0..3} -> plain row-major slot
            p.x = packh2(acc[0], acc[1]);
            p.y = packh2(acc[2], acc[3]);
            Gpk2[(size_t)node * 32 + ot * 4 + quad] = p;
        }
    }
}

// ---------------------------------------------------------------------------
// Kernel 2: out[n] = tanh(sum_{e: dst=n} G[src_e] + b). One wave per node,
// 4 edge-groups x 16 lanes; lane reads uint4 = 8 fp16 cols (plain layout).
// j-loop is WAVE-UNIFORM so ds_bpermute (__shfl) always runs with all 64
// lanes active (R8 bug). Bias + tanh + contiguous float4 stores by group 0.
__global__ __launch_bounds__(256) void gather_tanh(const uint4* __restrict__ Gpk4,
                                                   const int* __restrict__ bucket,
                                                   const int* __restrict__ cursor,
                                                   const float* __restrict__ bias,
                                                   float* __restrict__ out) {
    const int wave = (blockIdx.x * 256 + threadIdx.x) >> 6;
    const int lane = threadIdx.x & 63;
    if (wave >= kNodes) return;
    const int grp = lane >> 4;      // 0..3 : edge group
    const int sub = lane & 15;      // 0..15 : cols [sub*8, sub*8+8)

    const int deg = min(cursor[wave * kCPad], kCap);
    const int base = wave * kCap;

    // one coalesced load of all edge ids for this node (deg <= 48 < 64)
    int eid = (lane < deg) ? bucket[base + lane] : 0;

    float acc[8];
#pragma unroll
    for (int i = 0; i < 8; ++i) acc[i] = 0.0f;

    const int iters = (deg + 3) >> 2;   // uniform across the wave
#pragma unroll 2
    for (int i = 0; i < iters; ++i) {
        const int j = grp + 4 * i;
        const bool valid = (j < deg);
        int s = __shfl(eid, valid ? j : 0);   // full exec mask -> defined
        if (valid) {
            uint4 u = Gpk4[(size_t)s * 16 + sub];       // 16B -> 8 fp16
            const __half2* hp = reinterpret_cast<const __half2*>(&u);
#pragma unroll
            for (int q = 0; q < 4; ++q) {
                float2 f = __half22float2(hp[q]);
                acc[2 * q]     += f.x;
                acc[2 * q + 1] += f.y;
            }
        }
    }

#pragma unroll
    for (int i = 0; i < 8; ++i) {
        acc[i] += __shfl_xor(acc[i], 16);
        acc[i] += __shfl_xor(acc[i], 32);
    }

    if (grp == 0) {
        float4 b0 = *reinterpret_cast<const float4*>(bias + sub * 8);
        float4 b1 = *reinterpret_cast<const float4*>(bias + sub * 8 + 4);
        float4 r0, r1;
        r0.x = 1.0f - 2.0f / (__expf(2.0f * (acc[0] + b0.x)) + 1.0f);
        r0.y = 1.0f - 2.0f / (__expf(2.0f * (acc[1] + b0.y)) + 1.0f);
        r0.z = 1.0f - 2.0f / (__expf(2.0f * (acc[2] + b0.z)) + 1.0f);
        r0.w = 1.0f - 2.0f / (__expf(2.0f * (acc[3] + b0.w)) + 1.0f);
        r1.x = 1.0f - 2.0f / (__expf(2.0f * (acc[4] + b1.x)) + 1.0f);
        r1.y = 1.0f - 2.0f / (__expf(2.0f * (acc[5] + b1.y)) + 1.0f);
        r1.z = 1.0f - 2.0f / (__expf(2.0f * (acc[6] + b1.z)) + 1.0f);
        r1.w = 1.0f - 2.0f / (__expf(2.0f * (acc[7] + b1.w)) + 1.0f);
        float4* dst = reinterpret_cast<float4*>(out + (size_t)wave * kF + sub * 8);
        dst[0] = r0;
        dst[1] = r1;
    }
}

// ---------------------------------------------------------------------------
// Fallback (vestigial — measured ws_size is 256 MiB): R1-style atomic scatter.
__global__ __launch_bounds__(256) void scatter_add(const float* __restrict__ feature,
                                                   const int* __restrict__ src,
                                                   const int* __restrict__ dst,
                                                   float* __restrict__ agg) {
    int gid = blockIdx.x * 256 + threadIdx.x;
    int e = gid >> 5;
    int c = (gid & 31) << 2;
    float4 v = *reinterpret_cast<const float4*>(feature + (size_t)src[e] * kF + c);
    float* p = agg + (size_t)dst[e] * kF + c;
    atomicAdd(p + 0, v.x);
    atomicAdd(p + 1, v.y);
    atomicAdd(p + 2, v.z);
    atomicAdd(p + 3, v.w);
}

__global__ __launch_bounds__(256, 4) void linear_tanh(float* __restrict__ inout,
                                                      const float* __restrict__ Wt,
                                                      const float* __restrict__ bias) {
    __shared__ float sAgg[kNPB * kF];
    __shared__ float sB[kF];
    const int t  = threadIdx.x;
    const int n0 = blockIdx.x * kNPB;
    if (t < kF) sB[t] = bias[t];
    const int rows = min(kNPB, kNodes - n0);
    for (int i = t * 4; i < rows * kF; i += 256 * 4)
        *reinterpret_cast<float4*>(&sAgg[i]) =
            *reinterpret_cast<const float4*>(inout + (size_t)n0 * kF + i);
    __syncthreads();
    const int tn = t >> 5, to = t & 31, nb = tn * 8;
    float acc[8][4];
#pragma unroll
    for (int n = 0; n < 8; ++n)
#pragma unroll
        for (int j = 0; j < 4; ++j) acc[n][j] = 0.0f;
    for (int k = 0; k < kF; k += 4) {
        float4 wt[4];
#pragma unroll
        for (int i = 0; i < 4; ++i)
            wt[i] = *reinterpret_cast<const float4*>(Wt + (k + i) * kF + to * 4);
#pragma unroll
        for (int n = 0; n < 8; ++n) {
            float4 av = *reinterpret_cast<const float4*>(&sAgg[(nb + n) * kF + k]);
#pragma unroll
            for (int j = 0; j < 4; ++j) {
                const float* w0 = reinterpret_cast<const float*>(&wt[0]);
                const float* w1 = reinterpret_cast<const float*>(&wt[1]);
                const float* w2 = reinterpret_cast<const float*>(&wt[2]);
                const float* w3 = reinterpret_cast<const float*>(&wt[3]);
                acc[n][j] += av.x * w0[j] + av.y * w1[j] + av.z * w2[j] + av.w * w3[j];
            }
        }
    }
#pragma unroll
    for (int n = 0; n < 8; ++n) {
        int node = n0 + nb + n;
        if (node < kNodes) {
            float4 r;
            r.x = 1.0f - 2.0f / (__expf(2.0f * (acc[n][0] + sB[to * 4 + 0])) + 1.0f);
            r.y = 1.0f - 2.0f / (__expf(2.0f * (acc[n][1] + sB[to * 4 + 1])) + 1.0f);
            r.z = 1.0f - 2.0f / (__expf(2.0f * (acc[n][2] + sB[to * 4 + 2])) + 1.0f);
            r.w = 1.0f - 2.0f / (__expf(2.0f * (acc[n][3] + sB[to * 4 + 3])) + 1.0f);
            *reinterpret_cast<float4*>(inout + (size_t)node * kF + to * 4) = r;
        }
    }
}

// ---------------------------------------------------------------------------
extern "C" void kernel_launch(void* const* d_in, const int* in_sizes, int n_in,
                              void* d_out, int out_size, void* d_ws, size_t ws_size,
                              hipStream_t stream) {
    const float* feature = (const float*)d_in[0];
    const float* W       = (const float*)d_in[1];
    const float* b       = (const float*)d_in[2];
    const int*   src     = (const int*)d_in[3];
    const int*   dst     = (const int*)d_in[4];
    float* out = (float*)d_out;

    char* ws = (char*)d_ws;
    float* Wt     = (float*)(ws + kOffWt);
    int*   cursor = (int*)(ws + kOffCursor);
    int*   bucket = (int*)(ws + kOffBucket);
    uint2* Gpk2   = (uint2*)(ws + kOffGpk);

    if (ws_size >= kWsNeeded) {   // ws_size constant across calls -> graph-safe
        prep0<<<(kNodes + 255) / 256, 256, 0, stream>>>(W, Wt, cursor);
        gemm_fill<<<kFillB + kGemmB, 256, 0, stream>>>(
            feature, W, src, dst, cursor, bucket, Gpk2);
        gather_tanh<<<(kNodes + 3) / 4, 256, 0, stream>>>(
            (const uint4*)Gpk2, bucket, cursor, b, out);
    } else {
        prep0<<<(kNodes + 255) / 256, 256, 0, stream>>>(W, Wt, cursor);
        hipMemsetAsync(out, 0, (size_t)kNodes * kF * sizeof(float), stream);
        scatter_add<<<(kEdges * 32) / 256, 256, 0, stream>>>(feature, src, dst, out);
        linear_tanh<<<(kNodes + kNPB - 1) / kNPB, 256, 0, stream>>>(out, Wt, b);
    }
}

// Round 13
// 150.455 us; speedup vs baseline: 1.0821x; 1.0821x over previous
//
#include <hip/hip_runtime.h>
#include <hip/hip_fp16.h>
#include <math.h>

constexpr int kNodes = 50000;
constexpr int kEdges = 600000;
constexpr int kF     = 128;
constexpr int kNPB   = 64;        // nodes per block in gemm
constexpr int kCap   = 48;        // fixed bucket capacity; P(deg>=48) ~ 3e-15/node
constexpr int kStr   = 136;       // LDS row stride in fp16 (272B: 16B-aligned, uniform banks)
constexpr int kCPad  = 16;        // cursor pad: one counter per 64B line

constexpr int kGemmB = (kNodes + kNPB - 1) / kNPB;   // 782
constexpr int kFillB = (kEdges + 255) / 256;         // 2344

// workspace layout (bytes)
constexpr size_t kOffWt     = 0;                          //  64 KB (fallback path only)
constexpr size_t kOffCursor = 65536;                      // 3.2 MB padded cursors
constexpr size_t kOffBucket = 65536 + 3200000;            // 9.6 MB
constexpr size_t kOffGpk    = kOffBucket + (size_t)kNodes * kCap * 4;   // 12.8 MB, 16B-aligned
constexpr size_t kWsNeeded  = kOffGpk + (size_t)kNodes * kF * 2;        // ~25 MiB

typedef _Float16 v8h __attribute__((ext_vector_type(8)));
typedef float    v4f __attribute__((ext_vector_type(4)));

static __device__ __forceinline__ unsigned int packh2(float a, float b) {
    __half2 h = __floats2half2_rn(a, b);
    return *reinterpret_cast<unsigned int*>(&h);
}

// ---------------------------------------------------------------------------
// Kernel 0: zero padded bucket cursors (64B/node) + Wt transpose (fallback).
__global__ __launch_bounds__(256) void prep0(const float* __restrict__ W,
                                             float* __restrict__ Wt,
                                             int* __restrict__ cursor) {
    int gid = blockIdx.x * 256 + threadIdx.x;    // grid covers 50176
    if (gid < kF * kF) {
        int k = gid >> 7;
        int o = gid & (kF - 1);
        Wt[gid] = W[o * kF + k];
    }
    if (gid < kNodes) {
        uint4 z = {0, 0, 0, 0};
        uint4* c4 = reinterpret_cast<uint4*>(cursor) + gid * 4;   // 64B line
        c4[0] = z; c4[1] = z; c4[2] = z; c4[3] = z;
    }
}

// ---------------------------------------------------------------------------
// Kernel 1: standalone bucket fill — NO LDS, tiny VGPR footprint => full
// 32-wave/CU occupancy (R12's fused version carried a dead 51KB LDS
// allocation per fill block, capping residency at 3 blocks/CU).
__global__ __launch_bounds__(256) void bucket_fill(const int* __restrict__ src,
                                                   const int* __restrict__ dst,
                                                   int* __restrict__ cursor,
                                                   int* __restrict__ bucket) {
    int e = blockIdx.x * 256 + threadIdx.x;
    if (e < kEdges) {
        int d = dst[e];
        int p = atomicAdd(&cursor[d * kCPad], 1);
        if (p < kCap) bucket[d * kCap + p] = src[e];   // guard: never triggers
    }
}

// ---------------------------------------------------------------------------
// Kernel 2: G = F @ W^T via MFMA fp16, packed fp16 row-major.
//   A-frag: lane holds W[ot*16 + (lane&15)][quad*8+j]  (b128 from padded sW)
//   B-frag: lane holds F[node][quad*8+j] read DIRECT from global (F has no
//           reuse within a block — LDS staging of F was pure overhead) with
//           in-register fp32->fp16 pack.
//   D:      lane holds D[quad*4+r][lane&15] -> 4 consecutive outs -> uint2.
// LDS = sW only (34.8 KB) => 4 blocks/CU.
__global__ __launch_bounds__(256, 4) void gemm_mfma(const float* __restrict__ F,
                                                    const float* __restrict__ Wg,
                                                    uint2* __restrict__ Gpk2) {
    __shared__ __align__(16) unsigned short sW[kF * kStr];     // 34.8 KB

    const int t = threadIdx.x;
    const int n0 = blockIdx.x * kNPB;

    const int wv   = t >> 6;       // wave id 0..3 -> node-tile
    const int lane = t & 63;
    const int m    = lane & 15;    // within-tile row/col index
    const int quad = lane >> 4;    // 0..3

    const int node = n0 + wv * 16 + m;            // this lane's node (D col)
    const int nrow = min(node, kNodes - 1);       // clamp OOB lanes' loads

    // B-frags direct from global (read once, reused across 8 out-tiles):
    // lane reads 8 fp32 = 32B at row nrow, k-offset kc*32+quad*8.
    const float* frow = F + (size_t)nrow * kF;
    v8h bfrag[4];
#pragma unroll
    for (int kc = 0; kc < 4; ++kc) {
        const float4* fp = reinterpret_cast<const float4*>(frow + kc * 32 + quad * 8);
        float4 f0 = fp[0], f1 = fp[1];
        uint4 pk;
        pk.x = packh2(f0.x, f0.y);
        pk.y = packh2(f0.z, f0.w);
        pk.z = packh2(f1.x, f1.y);
        pk.w = packh2(f1.z, f1.w);
        union { uint4 u; v8h h; } cvt;
        cvt.u = pk;
        bfrag[kc] = cvt.h;
    }

    // stage W (fp32 global, L2-hot) -> fp16 LDS row-major, stride kStr
    for (int idx = t; idx < kF * 16; idx += 256) {       // 8 iters
        int o = idx >> 4, c = idx & 15;
        const float4* wp = reinterpret_cast<const float4*>(Wg + o * kF + c * 8);
        float4 w0 = wp[0], w1 = wp[1];
        uint4 pk;
        pk.x = packh2(w0.x, w0.y);
        pk.y = packh2(w0.z, w0.w);
        pk.z = packh2(w1.x, w1.y);
        pk.w = packh2(w1.z, w1.w);
        *reinterpret_cast<uint4*>(&sW[o * kStr + c * 8]) = pk;
    }
    __syncthreads();

#pragma unroll
    for (int ot = 0; ot < 8; ++ot) {
        v4f acc = {0.0f, 0.0f, 0.0f, 0.0f};
#pragma unroll
        for (int kc = 0; kc < 4; ++kc) {
            v8h afrag = *reinterpret_cast<const v8h*>(&sW[(ot * 16 + m) * kStr + kc * 32 + quad * 8]);
            acc = __builtin_amdgcn_mfma_f32_16x16x32_f16(afrag, bfrag[kc], acc, 0, 0, 0);
        }
        if (node < kNodes) {
            uint2 p;   // outs ot*16 + quad*4 + {0..3} -> plain row-major slot
            p.x = packh2(acc[0], acc[1]);
            p.y = packh2(acc[2], acc[3]);
            Gpk2[(size_t)node * 32 + ot * 4 + quad] = p;
        }
    }
}

// ---------------------------------------------------------------------------
// Kernel 3: out[n] = tanh(sum_{e: dst=n} G[src_e] + b). One wave per node,
// 4 edge-groups x 16 lanes; lane reads uint4 = 8 fp16 cols (plain layout).
// j-loop is WAVE-UNIFORM so ds_bpermute (__shfl) always runs with all 64
// lanes active (R8 bug). Bias + tanh + contiguous float4 stores by group 0.
__global__ __launch_bounds__(256) void gather_tanh(const uint4* __restrict__ Gpk4,
                                                   const int* __restrict__ bucket,
                                                   const int* __restrict__ cursor,
                                                   const float* __restrict__ bias,
                                                   float* __restrict__ out) {
    const int wave = (blockIdx.x * 256 + threadIdx.x) >> 6;
    const int lane = threadIdx.x & 63;
    if (wave >= kNodes) return;
    const int grp = lane >> 4;      // 0..3 : edge group
    const int sub = lane & 15;      // 0..15 : cols [sub*8, sub*8+8)

    const int deg = min(cursor[wave * kCPad], kCap);
    const int base = wave * kCap;

    // one coalesced load of all edge ids for this node (deg <= 48 < 64)
    int eid = (lane < deg) ? bucket[base + lane] : 0;

    float acc[8];
#pragma unroll
    for (int i = 0; i < 8; ++i) acc[i] = 0.0f;

    const int iters = (deg + 3) >> 2;   // uniform across the wave
#pragma unroll 2
    for (int i = 0; i < iters; ++i) {
        const int j = grp + 4 * i;
        const bool valid = (j < deg);
        int s = __shfl(eid, valid ? j : 0);   // full exec mask -> defined
        if (valid) {
            uint4 u = Gpk4[(size_t)s * 16 + sub];       // 16B -> 8 fp16
            const __half2* hp = reinterpret_cast<const __half2*>(&u);
#pragma unroll
            for (int q = 0; q < 4; ++q) {
                float2 f = __half22float2(hp[q]);
                acc[2 * q]     += f.x;
                acc[2 * q + 1] += f.y;
            }
        }
    }

#pragma unroll
    for (int i = 0; i < 8; ++i) {
        acc[i] += __shfl_xor(acc[i], 16);
        acc[i] += __shfl_xor(acc[i], 32);
    }

    if (grp == 0) {
        float4 b0 = *reinterpret_cast<const float4*>(bias + sub * 8);
        float4 b1 = *reinterpret_cast<const float4*>(bias + sub * 8 + 4);
        float4 r0, r1;
        r0.x = 1.0f - 2.0f / (__expf(2.0f * (acc[0] + b0.x)) + 1.0f);
        r0.y = 1.0f - 2.0f / (__expf(2.0f * (acc[1] + b0.y)) + 1.0f);
        r0.z = 1.0f - 2.0f / (__expf(2.0f * (acc[2] + b0.z)) + 1.0f);
        r0.w = 1.0f - 2.0f / (__expf(2.0f * (acc[3] + b0.w)) + 1.0f);
        r1.x = 1.0f - 2.0f / (__expf(2.0f * (acc[4] + b1.x)) + 1.0f);
        r1.y = 1.0f - 2.0f / (__expf(2.0f * (acc[5] + b1.y)) + 1.0f);
        r1.z = 1.0f - 2.0f / (__expf(2.0f * (acc[6] + b1.z)) + 1.0f);
        r1.w = 1.0f - 2.0f / (__expf(2.0f * (acc[7] + b1.w)) + 1.0f);
        float4* dst = reinterpret_cast<float4*>(out + (size_t)wave * kF + sub * 8);
        dst[0] = r0;
        dst[1] = r1;
    }
}

// ---------------------------------------------------------------------------
// Fallback (vestigial — measured ws_size is 256 MiB): R1-style atomic scatter.
__global__ __launch_bounds__(256) void scatter_add(const float* __restrict__ feature,
                                                   const int* __restrict__ src,
                                                   const int* __restrict__ dst,
                                                   float* __restrict__ agg) {
    int gid = blockIdx.x * 256 + threadIdx.x;
    int e = gid >> 5;
    int c = (gid & 31) << 2;
    float4 v = *reinterpret_cast<const float4*>(feature + (size_t)src[e] * kF + c);
    float* p = agg + (size_t)dst[e] * kF + c;
    atomicAdd(p + 0, v.x);
    atomicAdd(p + 1, v.y);
    atomicAdd(p + 2, v.z);
    atomicAdd(p + 3, v.w);
}

__global__ __launch_bounds__(256, 4) void linear_tanh(float* __restrict__ inout,
                                                      const float* __restrict__ Wt,
                                                      const float* __restrict__ bias) {
    __shared__ float sAgg[kNPB * kF];
    __shared__ float sB[kF];
    const int t  = threadIdx.x;
    const int n0 = blockIdx.x * kNPB;
    if (t < kF) sB[t] = bias[t];
    const int rows = min(kNPB, kNodes - n0);
    for (int i = t * 4; i < rows * kF; i += 256 * 4)
        *reinterpret_cast<float4*>(&sAgg[i]) =
            *reinterpret_cast<const float4*>(inout + (size_t)n0 * kF + i);
    __syncthreads();
    const int tn = t >> 5, to = t & 31, nb = tn * 8;
    float acc[8][4];
#pragma unroll
    for (int n = 0; n < 8; ++n)
#pragma unroll
        for (int j = 0; j < 4; ++j) acc[n][j] = 0.0f;
    for (int k = 0; k < kF; k += 4) {
        float4 wt[4];
#pragma unroll
        for (int i = 0; i < 4; ++i)
            wt[i] = *reinterpret_cast<const float4*>(Wt + (k + i) * kF + to * 4);
#pragma unroll
        for (int n = 0; n < 8; ++n) {
            float4 av = *reinterpret_cast<const float4*>(&sAgg[(nb + n) * kF + k]);
#pragma unroll
            for (int j = 0; j < 4; ++j) {
                const float* w0 = reinterpret_cast<const float*>(&wt[0]);
                const float* w1 = reinterpret_cast<const float*>(&wt[1]);
                const float* w2 = reinterpret_cast<const float*>(&wt[2]);
                const float* w3 = reinterpret_cast<const float*>(&wt[3]);
                acc[n][j] += av.x * w0[j] + av.y * w1[j] + av.z * w2[j] + av.w * w3[j];
            }
        }
    }
#pragma unroll
    for (int n = 0; n < 8; ++n) {
        int node = n0 + nb + n;
        if (node < kNodes) {
            float4 r;
            r.x = 1.0f - 2.0f / (__expf(2.0f * (acc[n][0] + sB[to * 4 + 0])) + 1.0f);
            r.y = 1.0f - 2.0f / (__expf(2.0f * (acc[n][1] + sB[to * 4 + 1])) + 1.0f);
            r.z = 1.0f - 2.0f / (__expf(2.0f * (acc[n][2] + sB[to * 4 + 2])) + 1.0f);
            r.w = 1.0f - 2.0f / (__expf(2.0f * (acc[n][3] + sB[to * 4 + 3])) + 1.0f);
            *reinterpret_cast<float4*>(inout + (size_t)node * kF + to * 4) = r;
        }
    }
}

// ---------------------------------------------------------------------------
extern "C" void kernel_launch(void* const* d_in, const int* in_sizes, int n_in,
                              void* d_out, int out_size, void* d_ws, size_t ws_size,
                              hipStream_t stream) {
    const float* feature = (const float*)d_in[0];
    const float* W       = (const float*)d_in[1];
    const float* b       = (const float*)d_in[2];
    const int*   src     = (const int*)d_in[3];
    const int*   dst     = (const int*)d_in[4];
    float* out = (float*)d_out;

    char* ws = (char*)d_ws;
    float* Wt     = (float*)(ws + kOffWt);
    int*   cursor = (int*)(ws + kOffCursor);
    int*   bucket = (int*)(ws + kOffBucket);
    uint2* Gpk2   = (uint2*)(ws + kOffGpk);

    if (ws_size >= kWsNeeded) {   // ws_size constant across calls -> graph-safe
        prep0<<<(kNodes + 255) / 256, 256, 0, stream>>>(W, Wt, cursor);
        bucket_fill<<<kFillB, 256, 0, stream>>>(src, dst, cursor, bucket);
        gemm_mfma<<<kGemmB, 256, 0, stream>>>(feature, W, Gpk2);
        gather_tanh<<<(kNodes + 3) / 4, 256, 0, stream>>>(
            (const uint4*)Gpk2, bucket, cursor, b, out);
    } else {
        prep0<<<(kNodes + 255) / 256, 256, 0, stream>>>(W, Wt, cursor);
        hipMemsetAsync(out, 0, (size_t)kNodes * kF * sizeof(float), stream);
        scatter_add<<<(kEdges * 32) / 256, 256, 0, stream>>>(feature, src, dst, out);
        linear_tanh<<<(kNodes + kNPB - 1) / kNPB, 256, 0, stream>>>(out, Wt, b);
    }
}